// Round 6
// baseline (241.689 us; speedup 1.0000x reference)
//
#include <hip/hip_runtime.h>
#include <math.h>

// RUL loss: out = theta * sum(score(diff)) + (1-theta) * sqrt(mean(diff^2))
// score(d) = (d<0 ? exp(-d/13) : exp(d/10)) - 1
// N = 16777216 fp32. 128 MB logical read.
//
// R5 result: dur invariant at ~43 us across occupancy 40-70% and load depth
// 2..16 => per-wave MLP falsified. Read rate pinned at ~3.1 TB/s = exactly
// the per-direction rate of the 6.29 TB/s copy ubench. Hypothesis: ~3.15 TB/s
// read-path ceiling. R6 discriminator: nt (non-temporal) loads -- if L3
// streaming-allocation was the throttle, FETCH_SIZE and dur drop; if the
// per-direction cap is real, dur stays ~43 us and we're at roofline
// (128 MB / 3.15 TB/s = 40.6 us). Also fuses the finalize via last-block
// ticket (saves one launch).

#define RUL_N 16777216
#define PART_BLOCKS 2048
#define BLOCK_THREADS 256
#define GRID_THREADS (PART_BLOCKS * BLOCK_THREADS)
#define ITERS ((RUL_N / 4) / GRID_THREADS)   // = 8, compile-time constant

typedef float v4f __attribute__((ext_vector_type(4)));

// vdst <- mem[sbase + voff], non-temporal (no L1/L2/MALL allocate).
// voff: 32-bit byte-offset VGPR; sbase: uniform SGPR pair. Earlyclobber dst.
#define GLOAD4_NT(dst, voff, sbase) \
    asm volatile("global_load_dwordx4 %0, %1, %2 nt" \
                 : "=&v"(dst) : "v"(voff), "s"(sbase))

#define PIN(x) asm volatile("" : "+v"(x))

__global__ __launch_bounds__(BLOCK_THREADS, 2) void rul_fused_kernel(
    const float* __restrict__ pred,
    const float* __restrict__ tru,
    const float* __restrict__ theta_ptr,
    float* __restrict__ out,
    float* __restrict__ partials /* [2*PART_BLOCKS] then uint counter */,
    unsigned int* __restrict__ counter) {

    const int tid = blockIdx.x * BLOCK_THREADS + threadIdx.x;
    const int v_byte = tid * 16;

    v4f p[ITERS];
    v4f t[ITERS];

#pragma unroll
    for (int k = 0; k < ITERS; ++k) {
        GLOAD4_NT(p[k], v_byte, pred + (size_t)k * GRID_THREADS * 4);
        GLOAD4_NT(t[k], v_byte, tru  + (size_t)k * GRID_THREADS * 4);
    }
    asm volatile("s_waitcnt vmcnt(0)" ::: "memory");
#pragma unroll
    for (int k = 0; k < ITERS; ++k) { PIN(p[k]); PIN(t[k]); }

    float s_score0 = 0.0f, s_score1 = 0.0f;
    float s_sq0 = 0.0f, s_sq1 = 0.0f;
#pragma unroll
    for (int k = 0; k < ITERS; ++k) {
        float d0 = p[k][0] - t[k][0];
        float d1 = p[k][1] - t[k][1];
        float d2 = p[k][2] - t[k][2];
        float d3 = p[k][3] - t[k][3];

        float e0 = __expf(d0 * (d0 < 0.0f ? (-1.0f / 13.0f) : (1.0f / 10.0f)));
        float e1 = __expf(d1 * (d1 < 0.0f ? (-1.0f / 13.0f) : (1.0f / 10.0f)));
        float e2 = __expf(d2 * (d2 < 0.0f ? (-1.0f / 13.0f) : (1.0f / 10.0f)));
        float e3 = __expf(d3 * (d3 < 0.0f ? (-1.0f / 13.0f) : (1.0f / 10.0f)));

        s_score0 += (e0 - 1.0f) + (e1 - 1.0f);
        s_score1 += (e2 - 1.0f) + (e3 - 1.0f);
        s_sq0 += d0 * d0 + d1 * d1;
        s_sq1 += d2 * d2 + d3 * d3;
    }
    float s_score = s_score0 + s_score1;
    float s_sq = s_sq0 + s_sq1;

    // wave-64 reduce
#pragma unroll
    for (int off = 32; off > 0; off >>= 1) {
        s_score += __shfl_down(s_score, off);
        s_sq += __shfl_down(s_sq, off);
    }

    __shared__ float sm_score[BLOCK_THREADS / 64];
    __shared__ float sm_sq[BLOCK_THREADS / 64];
    __shared__ int sm_last;
    const int wave = threadIdx.x >> 6;
    const int lane = threadIdx.x & 63;
    if (lane == 0) {
        sm_score[wave] = s_score;
        sm_sq[wave] = s_sq;
    }
    __syncthreads();
    if (threadIdx.x == 0) {
        float a = 0.0f, b = 0.0f;
#pragma unroll
        for (int w = 0; w < BLOCK_THREADS / 64; ++w) {
            a += sm_score[w];
            b += sm_sq[w];
        }
        partials[blockIdx.x] = a;
        partials[PART_BLOCKS + blockIdx.x] = b;
        __threadfence();  // publish partials device-scope before ticket
        unsigned int ticket = atomicAdd(counter, 1u);
        sm_last = (ticket == PART_BLOCKS - 1) ? 1 : 0;
    }
    __syncthreads();

    if (sm_last) {
        __threadfence();  // acquire: all partials visible
        float a = 0.0f, b = 0.0f;
#pragma unroll
        for (int i = threadIdx.x; i < PART_BLOCKS; i += BLOCK_THREADS) {
            a += partials[i];
            b += partials[PART_BLOCKS + i];
        }
#pragma unroll
        for (int off = 32; off > 0; off >>= 1) {
            a += __shfl_down(a, off);
            b += __shfl_down(b, off);
        }
        if (lane == 0) {
            sm_score[wave] = a;
            sm_sq[wave] = b;
        }
        __syncthreads();
        if (threadIdx.x == 0) {
            float sa = 0.0f, sb = 0.0f;
#pragma unroll
            for (int w = 0; w < BLOCK_THREADS / 64; ++w) {
                sa += sm_score[w];
                sb += sm_sq[w];
            }
            float theta = theta_ptr[0];
            float rmse = sqrtf(sb * (1.0f / (float)RUL_N));
            out[0] = theta * sa + (1.0f - theta) * rmse;
        }
    }
}

extern "C" void kernel_launch(void* const* d_in, const int* in_sizes, int n_in,
                              void* d_out, int out_size, void* d_ws, size_t ws_size,
                              hipStream_t stream) {
    const float* pred = (const float*)d_in[0];
    const float* tru = (const float*)d_in[1];
    const float* theta = (const float*)d_in[2];
    float* out = (float*)d_out;
    float* partials = (float*)d_ws;                       // 2*PART_BLOCKS floats
    unsigned int* counter = (unsigned int*)((char*)d_ws + 2 * PART_BLOCKS * sizeof(float));

    // ws is poisoned to 0xAA before every launch: zero the ticket counter.
    hipMemsetAsync(counter, 0, sizeof(unsigned int), stream);

    rul_fused_kernel<<<PART_BLOCKS, BLOCK_THREADS, 0, stream>>>(
        pred, tru, theta, out, partials, counter);
}